// Round 12
// baseline (123.907 us; speedup 1.0000x reference)
//
#include <hip/hip_runtime.h>
#include <hip/hip_bf16.h>
#include <math.h>

#define EPSF 1e-5f

typedef __attribute__((ext_vector_type(8))) short short8;
typedef __attribute__((ext_vector_type(4))) float f32x4;
typedef _Float16 half8 __attribute__((ext_vector_type(8)));

constexpr int Bc = 4, Tc = 512, Dc = 1024, Mc = 128, Hc = 8, DAc = 64, DMc = 128;
constexpr int BT = Bc * Tc;      // 2048
constexpr int Xc = DAc * DMc;    // 8192
constexpr int Rb = Tc * Hc;      // 4096 rows per batch (t*8+h)

__device__ __forceinline__ float softplus_f(float x) {
    return fmaxf(x, 0.f) + log1pf(expf(-fabsf(x)));
}
__device__ __forceinline__ short f2bf(float f) {
    __hip_bfloat16 h = __float2bfloat16(f);
    return *reinterpret_cast<short*>(&h);
}
__device__ __forceinline__ unsigned pk2(float a, float b) {
    return (unsigned)(unsigned short)f2bf(a) | ((unsigned)(unsigned short)f2bf(b) << 16);
}
// async global->LDS, 16B per lane; lds base must be wave-uniform
__device__ __forceinline__ void lds_load16(void* lds, const void* g) {
    __builtin_amdgcn_global_load_lds((const __attribute__((address_space(1))) int*)g,
                                     (__attribute__((address_space(3))) int*)lds, 16, 0, 0);
}

// ---------------- front: k1t | k2 | norm_k | convq | tW --------------------------------
__global__ __launch_bounds__(256) void front_kern(
        const float* __restrict__ addresses,
        const float* __restrict__ matrix,
        const float* __restrict__ normalizer,
        const float* __restrict__ query,
        const float* __restrict__ W_access,
        const float* __restrict__ W_read,
        const float* __restrict__ W_merge,
        _Float16* __restrict__ kern2,
        float* __restrict__ kern_n,
        float* __restrict__ norm_k,
        __hip_bfloat16* __restrict__ qb,
        __hip_bfloat16* __restrict__ WpT,
        __hip_bfloat16* __restrict__ WmT) {
    __shared__ float smem[8192];   // 32KB, carved per branch
    int bid = blockIdx.x;
    int tid = threadIdx.x;

    if (bid < 256) {
        // ---- k1t: kern2[b][a][m][a2] = sum_mm matrix[b][mm][a][m]*softplus(addr[mm][a2])
        float (*T)[132] = (float(*)[132])smem;
        _Float16 (*At)[40] = (_Float16(*)[40])(smem + 4224);
        int lane = tid & 63, wid = tid >> 6;
        int l15 = lane & 15, lg = lane >> 4;
        int b = bid >> 6, a = bid & 63;
        int wr = wid & 1, wc = wid >> 1;

        half8 bfrag[2][4];
#pragma unroll
        for (int cf = 0; cf < 2; cf++) {
            int a2 = wc * 32 + cf * 16 + l15;
#pragma unroll
            for (int ks = 0; ks < 4; ks++)
#pragma unroll
                for (int j = 0; j < 8; j++) {
                    int mm = ks * 32 + lg * 8 + j;
                    bfrag[cf][ks][j] = (_Float16)softplus_f(addresses[mm * 64 + a2]);
                }
        }

        const float* msrc = matrix + (size_t)b * Mc * Xc + a * DMc;
        int r = tid >> 3, ms = (tid & 7) * 16;
        int tm = tid >> 1, tk0 = (tid & 1) * 16;

        f32x4 acc[4][2];
#pragma unroll
        for (int i = 0; i < 4; i++)
#pragma unroll
            for (int j = 0; j < 2; j++) acc[i][j] = (f32x4){0.f, 0.f, 0.f, 0.f};

        float4 ld[4];
#pragma unroll
        for (int j = 0; j < 4; j++)
            ld[j] = *(const float4*)(msrc + (size_t)r * Xc + ms + j * 4);

        for (int s = 0; s < 4; s++) {
#pragma unroll
            for (int j = 0; j < 4; j++) *(float4*)&T[r][ms + j * 4] = ld[j];
            __syncthreads();
            if (s < 3) {
#pragma unroll
                for (int j = 0; j < 4; j++)
                    ld[j] = *(const float4*)(msrc + (size_t)((s + 1) * 32 + r) * Xc + ms + j * 4);
            }
            {
                half8 lo, hi;
#pragma unroll
                for (int j = 0; j < 8; j++) lo[j] = (_Float16)T[tk0 + j][tm];
#pragma unroll
                for (int j = 0; j < 8; j++) hi[j] = (_Float16)T[tk0 + 8 + j][tm];
                *(half8*)&At[tm][tk0] = lo;
                *(half8*)&At[tm][tk0 + 8] = hi;
            }
            __syncthreads();
#pragma unroll
            for (int rf = 0; rf < 4; rf++) {
                int row = wr * 64 + rf * 16 + l15;
                half8 af = *(const half8*)&At[row][lg * 8];
#pragma unroll
                for (int cf = 0; cf < 2; cf++)
                    acc[rf][cf] = __builtin_amdgcn_mfma_f32_16x16x32_f16(
                        af, bfrag[cf][s], acc[rf][cf], 0, 0, 0);
            }
            __syncthreads();
        }
        _Float16* dst = kern2 + ((size_t)(b * 64 + a)) * Mc * DAc;
#pragma unroll
        for (int rf = 0; rf < 4; rf++)
#pragma unroll
            for (int cf = 0; cf < 2; cf++) {
                int a2 = wc * 32 + cf * 16 + l15;
#pragma unroll
                for (int i = 0; i < 4; i++) {
                    int mrow = wr * 64 + rf * 16 + lg * 4 + i;
                    dst[mrow * DAc + a2] = (_Float16)acc[rf][cf][i];
                }
            }
        return;
    }
    if (bid < 288) {
        // ---- k2
        int idx = bid - 256;
        int b = idx >> 3, ch = idx & 7;
        for (int i = tid; i < Mc * DAc; i += 256) smem[i] = softplus_f(addresses[i]);
        __syncthreads();
        int d = tid & 63;
        int g = tid >> 6;
        int a2b = ch * 8 + g * 2;
        float acc0 = 0.f, acc1 = 0.f;
        const float* np = normalizer + (size_t)b * Mc * DAc + d;
        for (int mm = 0; mm < Mc; mm++) {
            float v = np[(size_t)mm * DAc];
            acc0 = fmaf(smem[mm * DAc + a2b + 0], v, acc0);
            acc1 = fmaf(smem[mm * DAc + a2b + 1], v, acc1);
        }
        kern_n[((size_t)b * DAc + a2b + 0) * DAc + d] = acc0;
        kern_n[((size_t)b * DAc + a2b + 1) * DAc + d] = acc1;
        return;
    }
    if (bid == 288) {
        // ---- norm_k
        for (int i = tid; i < Mc * DAc; i += 256) smem[i] = softplus_f(addresses[i]);
        __syncthreads();
        if (tid < DAc) {
            float s = 0.f;
            for (int mm = 0; mm < Mc; mm++) s += smem[mm * DAc + tid];
            norm_k[tid] = s;
        }
        return;
    }
    if (bid < 2337) {
        // ---- convq
        int i = ((bid - 289) * 256 + tid) * 4;
        float4 v = *(const float4*)(query + i);
        unsigned* d = (unsigned*)(qb + i);
        d[0] = pk2(v.x, v.y);
        d[1] = pk2(v.z, v.w);
        return;
    }
    // ---- tW
    float (*tile)[65] = (float(*)[65])smem;
    const float* S; int stride, nb, n0, kt;
    __hip_bfloat16* dst;
    if (bid < 2593) {
        int idx = bid - 2337;
        kt = idx & 15;
        n0 = (idx >> 4) * 64;
        if (n0 < 512) { S = W_access; nb = n0; }
        else          { S = W_read;   nb = n0 - 512; }
        stride = 512;
        dst = WpT;
    } else {
        int idx = bid - 2593;
        kt = idx & 15;
        n0 = (idx >> 4) * 64;
        S = W_merge; nb = n0; stride = 1024;
        dst = WmT;
    }
    {
        int kl = tid >> 2, q = tid & 3;
        const float* src = S + (size_t)(kt * 64 + kl) * stride + nb + q * 16;
#pragma unroll
        for (int j = 0; j < 4; j++) {
            float4 v = *(const float4*)(src + j * 4);
            tile[kl][q * 16 + j * 4 + 0] = v.x;
            tile[kl][q * 16 + j * 4 + 1] = v.y;
            tile[kl][q * 16 + j * 4 + 2] = v.z;
            tile[kl][q * 16 + j * 4 + 3] = v.w;
        }
    }
    __syncthreads();
    {
        int nl = tid >> 2, q = tid & 3;
        unsigned* d = (unsigned*)(dst + (size_t)(n0 + nl) * 1024 + kt * 64 + q * 16);
#pragma unroll
        for (int j = 0; j < 8; j++)
            d[j] = pk2(tile[q * 16 + j * 2][nl], tile[q * 16 + j * 2 + 1][nl]);
    }
}

// ---------------- bf16 MFMA GEMM: BM=64, BN=64, BK=128; grid (32,16) -------------------
template <bool SOFTPLUS, typename OutT>
__global__ __launch_bounds__(256) void gemm_bf16(const __hip_bfloat16* __restrict__ A,
                                                 const __hip_bfloat16* __restrict__ BT_,
                                                 const float* __restrict__ bias0,
                                                 const float* __restrict__ bias1, int N0,
                                                 OutT* __restrict__ C, int N, int K) {
    __shared__ short Ab[2][2][64 * 64];
    __shared__ short Bb[2][2][64 * 64];
    int tid = threadIdx.x, lane = tid & 63, wid = tid >> 6;
    int l15 = lane & 15, lg = lane >> 4;
    int rowblk = blockIdx.x * 64, colblk = blockIdx.y * 64;
    int wr = wid & 1, wc = wid >> 1;
    int srow = lane >> 3;
    int sk = ((lane & 7) ^ srow) * 8;

    f32x4 acc[2][2];
#pragma unroll
    for (int i = 0; i < 2; i++)
#pragma unroll
        for (int j = 0; j < 2; j++) acc[i][j] = (f32x4){0.f, 0.f, 0.f, 0.f};

    auto stage = [&](int kbase, int buf, int sub) {
#pragma unroll
        for (int j = 0; j < 2; j++) {
            int c = wid * 2 + j;
            int row = c * 8 + srow;
            lds_load16(&Ab[buf][sub][c * 512], A + (size_t)(rowblk + row) * K + kbase + sk);
            lds_load16(&Bb[buf][sub][c * 512], BT_ + (size_t)(colblk + row) * K + kbase + sk);
        }
    };
    stage(0, 0, 0);
    stage(64, 0, 1);
    __syncthreads();
    int cur = 0;
    int nks = K >> 7;   // 8
    for (int ks = 0; ks < nks; ks++) {
        if (ks + 1 < nks) {
            stage((ks + 1) << 7, cur ^ 1, 0);
            stage(((ks + 1) << 7) + 64, cur ^ 1, 1);
        }
#pragma unroll
        for (int sub = 0; sub < 2; sub++) {
#pragma unroll
            for (int kh = 0; kh < 2; kh++) {
                short8 af[2], bfr[2];
#pragma unroll
                for (int rf = 0; rf < 2; rf++) {
                    int row = wr * 32 + rf * 16 + l15;
                    int ksw = (kh * 32 + lg * 8) ^ ((row & 7) << 3);
                    af[rf] = *(const short8*)&Ab[cur][sub][row * 64 + ksw];
                }
#pragma unroll
                for (int cf = 0; cf < 2; cf++) {
                    int col = wc * 32 + cf * 16 + l15;
                    int ksw = (kh * 32 + lg * 8) ^ ((col & 7) << 3);
                    bfr[cf] = *(const short8*)&Bb[cur][sub][col * 64 + ksw];
                }
#pragma unroll
                for (int rf = 0; rf < 2; rf++)
#pragma unroll
                    for (int cf = 0; cf < 2; cf++)
                        acc[rf][cf] = __builtin_amdgcn_mfma_f32_16x16x32_bf16(
                            af[rf], bfr[cf], acc[rf][cf], 0, 0, 0);
            }
        }
        __syncthreads();
        cur ^= 1;
    }
#pragma unroll
    for (int cf = 0; cf < 2; cf++) {
        int col = colblk + wc * 32 + cf * 16 + l15;
        float bv = (col < N0) ? bias0[col] : bias1[col - N0];
#pragma unroll
        for (int rf = 0; rf < 2; rf++) {
            int rbase = rowblk + wr * 32 + rf * 16 + lg * 4;
#pragma unroll
            for (int i = 0; i < 4; i++) {
                float v = acc[rf][cf][i] + bv;
                if (SOFTPLUS) v = softplus_f(v);
                C[(size_t)(rbase + i) * N + col] = (OutT)v;
            }
        }
    }
}

// ---------------- k4: reg-staged B (no LDS for kern2), barrier-free main loop ----------
// num[row,m] = sum_a rq[row,a] * sum_a2 aq[row,a2] * kern2[b][a][m][a2]
__global__ __launch_bounds__(256) void k4_mfma(const _Float16* __restrict__ aqrq16,
                                               const _Float16* __restrict__ kern2,
                                               const float* __restrict__ kern_n,
                                               const float* __restrict__ norm_k,
                                               __hip_bfloat16* __restrict__ resp) {
    __shared__ _Float16 rql[64][72];        // 9.2KB
    __shared__ float knl[4096];             // 16KB
    __shared__ float scl[64];
    __shared__ float nkl[64];
    int tid = threadIdx.x, lane = tid & 63, wid = tid >> 6;
    int l15 = lane & 15, lg = lane >> 4;
    int b = blockIdx.x >> 7;
    int rc = (blockIdx.x >> 1) & 63;
    int mh = blockIdx.x & 1;
    int rowbase = rc * 64;
    int wr = wid & 1, wc = wid >> 1;

    // per-lane base into kern2 for B-fragments: [m][a2], lane reads 16B
    const _Float16* k2base = kern2 + ((size_t)b * 64 * Mc + mh * 64) * DAc
                             + (wc * 32 + l15) * DAc + lg * 8;
    // Bf[slot][kh][cf] : 4-deep prefetch ring, all-static indexing
    half8 Bf[4][2][2];
    auto loadB = [&](int a_, int slot) {
        const _Float16* p = k2base + (size_t)a_ * Mc * DAc;
#pragma unroll
        for (int kh = 0; kh < 2; kh++)
#pragma unroll
            for (int cf = 0; cf < 2; cf++)
                Bf[slot][kh][cf] = *(const half8*)(p + cf * 16 * DAc + kh * 32);
    };
    loadB(0, 0); loadB(1, 1); loadB(2, 2); loadB(3, 3);

    {   // kern_n[b] -> knl (16KB, async)
#pragma unroll
        for (int j = 0; j < 4; j++) {
            int c = wid * 4 + j;
            lds_load16(knl + c * 256, kern_n + (size_t)b * 4096 + c * 256 + lane * 4);
        }
    }
    // aq fragments (loop-invariant): 2 row-frags x 2 k-halves
    half8 aqp[2][2];
#pragma unroll
    for (int rf = 0; rf < 2; rf++)
#pragma unroll
        for (int kh = 0; kh < 2; kh++) {
            int rg = rowbase + wr * 32 + rf * 16 + l15;
            int t_ = rg >> 3, h = rg & 7;
            aqp[rf][kh] = *(const half8*)(aqrq16 + ((size_t)(b * Tc + t_)) * 1024
                                          + h * 64 + kh * 32 + lg * 8);
        }
    {   // rq rows -> LDS f16 (16 halves per thread)
        int row = tid >> 2, q = tid & 3;
        int rg = rowbase + row;
        int t_ = rg >> 3, h = rg & 7;
        const _Float16* src = aqrq16 + ((size_t)(b * Tc + t_)) * 1024 + 512 + h * 64 + q * 16;
        *(half8*)&rql[row][q * 16] = *(const half8*)(src);
        *(half8*)&rql[row][q * 16 + 8] = *(const half8*)(src + 8);
    }
    if (tid < 64) nkl[tid] = norm_k[tid];
    __syncthreads();

    // ---- scale phase: wave handles 16 rows x 4 d-chunks; knl reads broadcast ----
    {
        int row = wid * 16 + (lane >> 2);
        int c = lane & 3;
        int rg = rowbase + row;
        int t_ = rg >> 3, h = rg & 7;
        const _Float16* aqg = aqrq16 + ((size_t)(b * Tc + t_)) * 1024 + h * 64;
        float accj[16];
#pragma unroll
        for (int j = 0; j < 16; j++) accj[j] = 0.f;
        float d1 = 0.f;
#pragma unroll
        for (int a2c = 0; a2c < 4; a2c++) {
            half8 aa0 = *(const half8*)(aqg + a2c * 16);
            half8 aa1 = *(const half8*)(aqg + a2c * 16 + 8);
            float aqv[16];
#pragma unroll
            for (int j = 0; j < 8; j++) { aqv[j] = (float)aa0[j]; aqv[8 + j] = (float)aa1[j]; }
#pragma unroll
            for (int a2l = 0; a2l < 16; a2l++) {
                int a2 = a2c * 16 + a2l;
                float av = aqv[a2l];
                d1 = fmaf(av, nkl[a2], d1);
                const float4* kr = (const float4*)(knl + a2 * 64 + c * 16);
#pragma unroll
                for (int j4 = 0; j4 < 4; j4++) {
                    float4 kv = kr[j4];
                    accj[j4 * 4 + 0] = fmaf(av, kv.x, accj[j4 * 4 + 0]);
                    accj[j4 * 4 + 1] = fmaf(av, kv.y, accj[j4 * 4 + 1]);
                    accj[j4 * 4 + 2] = fmaf(av, kv.z, accj[j4 * 4 + 2]);
                    accj[j4 * 4 + 3] = fmaf(av, kv.w, accj[j4 * 4 + 3]);
                }
            }
        }
        float sn = 0.f;
#pragma unroll
        for (int j = 0; j < 16; j++)
            sn = fmaf((float)rql[row][c * 16 + j], accj[j], sn);
        sn += __shfl_xor(sn, 1);
        sn += __shfl_xor(sn, 2);
        if (c == 0) {
            float den1 = d1 + EPSF;
            float den = sn / den1 + EPSF;
            scl[row] = 1.f / (den1 * den);
        }
    }
    __syncthreads();   // scl ready

    f32x4 acc[2][2];
#pragma unroll
    for (int i = 0; i < 2; i++)
#pragma unroll
        for (int j = 0; j < 2; j++) acc[i][j] = (f32x4){0.f, 0.f, 0.f, 0.f};

    // ---- main loop: barrier-free, 4-slot register ring, unroll-4 for static slots ----
    for (int it = 0; it < 16; it++) {
#pragma unroll
        for (int s = 0; s < 4; s++) {
            int a = it * 4 + s;
            _Float16 h0 = rql[wr * 32 + l15][a];
            _Float16 h1 = rql[wr * 32 + 16 + l15][a];
            half8 rb0 = {h0, h0, h0, h0, h0, h0, h0, h0};
            half8 rb1 = {h1, h1, h1, h1, h1, h1, h1, h1};
#pragma unroll
            for (int kh = 0; kh < 2; kh++) {
                half8 a0 = aqp[0][kh] * rb0;
                half8 a1 = aqp[1][kh] * rb1;
#pragma unroll
                for (int cf = 0; cf < 2; cf++) {
                    acc[0][cf] = __builtin_amdgcn_mfma_f32_16x16x32_f16(
                        a0, Bf[s][kh][cf], acc[0][cf], 0, 0, 0);
                    acc[1][cf] = __builtin_amdgcn_mfma_f32_16x16x32_f16(
                        a1, Bf[s][kh][cf], acc[1][cf], 0, 0, 0);
                }
            }
            if (it < 15) loadB(a + 4, s);
        }
    }
#pragma unroll
    for (int rf = 0; rf < 2; rf++) {
#pragma unroll
        for (int i = 0; i < 4; i++) {
            int rl = wr * 32 + rf * 16 + lg * 4 + i;
            int rg = rowbase + rl;
            float s = scl[rl];
            int t_ = rg >> 3, h = rg & 7;
            __hip_bfloat16* dst = resp + ((size_t)(b * Tc + t_)) * 1024 + h * DMc + mh * 64;
#pragma unroll
            for (int cf = 0; cf < 2; cf++) {
                int m = wc * 32 + cf * 16 + l15;
                dst[m] = __float2bfloat16(acc[rf][cf][i] * s);
            }
        }
    }
}

extern "C" void kernel_launch(void* const* d_in, const int* in_sizes, int n_in,
                              void* d_out, int out_size, void* d_ws, size_t ws_size,
                              hipStream_t stream) {
    const float* query      = (const float*)d_in[0];
    const float* matrix     = (const float*)d_in[1];
    const float* normalizer = (const float*)d_in[2];
    const float* addresses  = (const float*)d_in[3];
    const float* W_access   = (const float*)d_in[4];
    const float* b_access   = (const float*)d_in[5];
    const float* W_read     = (const float*)d_in[6];
    const float* b_read     = (const float*)d_in[7];
    const float* W_merge    = (const float*)d_in[8];
    const float* b_merge    = (const float*)d_in[9];
    float* out = (float*)d_out;
    (void)in_sizes; (void)n_in; (void)out_size; (void)ws_size;

    float* ws     = (float*)d_ws;
    float* norm_k = ws;                        // 64 (+pad to 128)
    float* kern_n = ws + 128;                  // 16384
    _Float16* aqrq16 = (_Float16*)(ws + 16512);               // 2,097,152 f16
    _Float16* kern2  = (_Float16*)(ws + 1065088);             // 2,097,152 f16
    __hip_bfloat16* qb   = (__hip_bfloat16*)(ws + 2113664);   // 2,097,152 bf16
    __hip_bfloat16* resp = (__hip_bfloat16*)(ws + 3162240);   // 2,097,152 bf16
    __hip_bfloat16* WpT  = (__hip_bfloat16*)(ws + 4210816);   // 1,048,576 bf16
    __hip_bfloat16* WmT  = (__hip_bfloat16*)(ws + 4735104);   // 1,048,576 bf16
    // total 5,259,392 floats = 21.0 MB

    hipLaunchKernelGGL(front_kern, dim3(2849), dim3(256), 0, stream,
                       addresses, matrix, normalizer, query,
                       W_access, W_read, W_merge,
                       kern2, kern_n, norm_k, qb, WpT, WmT);
    hipLaunchKernelGGL((gemm_bf16<true, _Float16>), dim3(32, 16), dim3(256), 0, stream,
                       qb, WpT, b_access, b_read, 512, aqrq16, 1024, 1024);
    hipLaunchKernelGGL(k4_mfma, dim3(512), dim3(256), 0, stream,
                       aqrq16, kern2, kern_n, norm_k, resp);
    hipLaunchKernelGGL((gemm_bf16<false, float>), dim3(32, 16), dim3(256), 0, stream,
                       resp, WmT, b_merge, b_merge, 2048, out, 1024, 1024);
}

// Round 13
// 94.523 us; speedup vs baseline: 1.3109x; 1.3109x over previous
//
#include <hip/hip_runtime.h>
#include <hip/hip_bf16.h>
#include <math.h>

#define EPSF 1e-5f

typedef __attribute__((ext_vector_type(8))) short short8;
typedef __attribute__((ext_vector_type(4))) float f32x4;
typedef _Float16 half8 __attribute__((ext_vector_type(8)));

constexpr int Bc = 4, Tc = 512, Dc = 1024, Mc = 128, Hc = 8, DAc = 64, DMc = 128;
constexpr int BT = Bc * Tc;      // 2048
constexpr int Xc = DAc * DMc;    // 8192
constexpr int Rb = Tc * Hc;      // 4096 rows per batch (t*8+h)

__device__ __forceinline__ float softplus_f(float x) {
    return fmaxf(x, 0.f) + log1pf(expf(-fabsf(x)));
}
__device__ __forceinline__ short f2bf(float f) {
    __hip_bfloat16 h = __float2bfloat16(f);
    return *reinterpret_cast<short*>(&h);
}
__device__ __forceinline__ unsigned pk2(float a, float b) {
    return (unsigned)(unsigned short)f2bf(a) | ((unsigned)(unsigned short)f2bf(b) << 16);
}
// async global->LDS, 16B per lane; lds base must be wave-uniform
__device__ __forceinline__ void lds_load16(void* lds, const void* g) {
    __builtin_amdgcn_global_load_lds((const __attribute__((address_space(1))) int*)g,
                                     (__attribute__((address_space(3))) int*)lds, 16, 0, 0);
}

// ---------------- front: k1t | k2 | norm_k | convq | tW --------------------------------
__global__ __launch_bounds__(256) void front_kern(
        const float* __restrict__ addresses,
        const float* __restrict__ matrix,
        const float* __restrict__ normalizer,
        const float* __restrict__ query,
        const float* __restrict__ W_access,
        const float* __restrict__ W_read,
        const float* __restrict__ W_merge,
        _Float16* __restrict__ kern2,
        float* __restrict__ kern_n,
        float* __restrict__ norm_k,
        __hip_bfloat16* __restrict__ qb,
        __hip_bfloat16* __restrict__ WpT,
        __hip_bfloat16* __restrict__ WmT) {
    __shared__ float smem[8192];   // 32KB, carved per branch
    int bid = blockIdx.x;
    int tid = threadIdx.x;

    if (bid < 256) {
        // ---- k1t: kern2[b][a][m][a2] = sum_mm matrix[b][mm][a][m]*softplus(addr[mm][a2])
        float (*T)[132] = (float(*)[132])smem;
        _Float16 (*At)[40] = (_Float16(*)[40])(smem + 4224);
        int lane = tid & 63, wid = tid >> 6;
        int l15 = lane & 15, lg = lane >> 4;
        int b = bid >> 6, a = bid & 63;
        int wr = wid & 1, wc = wid >> 1;

        half8 bfrag[2][4];
#pragma unroll
        for (int cf = 0; cf < 2; cf++) {
            int a2 = wc * 32 + cf * 16 + l15;
#pragma unroll
            for (int ks = 0; ks < 4; ks++)
#pragma unroll
                for (int j = 0; j < 8; j++) {
                    int mm = ks * 32 + lg * 8 + j;
                    bfrag[cf][ks][j] = (_Float16)softplus_f(addresses[mm * 64 + a2]);
                }
        }

        const float* msrc = matrix + (size_t)b * Mc * Xc + a * DMc;
        int r = tid >> 3, ms = (tid & 7) * 16;
        int tm = tid >> 1, tk0 = (tid & 1) * 16;

        f32x4 acc[4][2];
#pragma unroll
        for (int i = 0; i < 4; i++)
#pragma unroll
            for (int j = 0; j < 2; j++) acc[i][j] = (f32x4){0.f, 0.f, 0.f, 0.f};

        float4 ld[4];
#pragma unroll
        for (int j = 0; j < 4; j++)
            ld[j] = *(const float4*)(msrc + (size_t)r * Xc + ms + j * 4);

        for (int s = 0; s < 4; s++) {
#pragma unroll
            for (int j = 0; j < 4; j++) *(float4*)&T[r][ms + j * 4] = ld[j];
            __syncthreads();
            if (s < 3) {
#pragma unroll
                for (int j = 0; j < 4; j++)
                    ld[j] = *(const float4*)(msrc + (size_t)((s + 1) * 32 + r) * Xc + ms + j * 4);
            }
            {
                half8 lo, hi;
#pragma unroll
                for (int j = 0; j < 8; j++) lo[j] = (_Float16)T[tk0 + j][tm];
#pragma unroll
                for (int j = 0; j < 8; j++) hi[j] = (_Float16)T[tk0 + 8 + j][tm];
                *(half8*)&At[tm][tk0] = lo;
                *(half8*)&At[tm][tk0 + 8] = hi;
            }
            __syncthreads();
#pragma unroll
            for (int rf = 0; rf < 4; rf++) {
                int row = wr * 64 + rf * 16 + l15;
                half8 af = *(const half8*)&At[row][lg * 8];
#pragma unroll
                for (int cf = 0; cf < 2; cf++)
                    acc[rf][cf] = __builtin_amdgcn_mfma_f32_16x16x32_f16(
                        af, bfrag[cf][s], acc[rf][cf], 0, 0, 0);
            }
            __syncthreads();
        }
        _Float16* dst = kern2 + ((size_t)(b * 64 + a)) * Mc * DAc;
#pragma unroll
        for (int rf = 0; rf < 4; rf++)
#pragma unroll
            for (int cf = 0; cf < 2; cf++) {
                int a2 = wc * 32 + cf * 16 + l15;
#pragma unroll
                for (int i = 0; i < 4; i++) {
                    int mrow = wr * 64 + rf * 16 + lg * 4 + i;
                    dst[mrow * DAc + a2] = (_Float16)acc[rf][cf][i];
                }
            }
        return;
    }
    if (bid < 288) {
        // ---- k2
        int idx = bid - 256;
        int b = idx >> 3, ch = idx & 7;
        for (int i = tid; i < Mc * DAc; i += 256) smem[i] = softplus_f(addresses[i]);
        __syncthreads();
        int d = tid & 63;
        int g = tid >> 6;
        int a2b = ch * 8 + g * 2;
        float acc0 = 0.f, acc1 = 0.f;
        const float* np = normalizer + (size_t)b * Mc * DAc + d;
        for (int mm = 0; mm < Mc; mm++) {
            float v = np[(size_t)mm * DAc];
            acc0 = fmaf(smem[mm * DAc + a2b + 0], v, acc0);
            acc1 = fmaf(smem[mm * DAc + a2b + 1], v, acc1);
        }
        kern_n[((size_t)b * DAc + a2b + 0) * DAc + d] = acc0;
        kern_n[((size_t)b * DAc + a2b + 1) * DAc + d] = acc1;
        return;
    }
    if (bid == 288) {
        // ---- norm_k
        for (int i = tid; i < Mc * DAc; i += 256) smem[i] = softplus_f(addresses[i]);
        __syncthreads();
        if (tid < DAc) {
            float s = 0.f;
            for (int mm = 0; mm < Mc; mm++) s += smem[mm * DAc + tid];
            norm_k[tid] = s;
        }
        return;
    }
    if (bid < 2337) {
        // ---- convq
        int i = ((bid - 289) * 256 + tid) * 4;
        float4 v = *(const float4*)(query + i);
        unsigned* d = (unsigned*)(qb + i);
        d[0] = pk2(v.x, v.y);
        d[1] = pk2(v.z, v.w);
        return;
    }
    // ---- tW
    float (*tile)[65] = (float(*)[65])smem;
    const float* S; int stride, nb, n0, kt;
    __hip_bfloat16* dst;
    if (bid < 2593) {
        int idx = bid - 2337;
        kt = idx & 15;
        n0 = (idx >> 4) * 64;
        if (n0 < 512) { S = W_access; nb = n0; }
        else          { S = W_read;   nb = n0 - 512; }
        stride = 512;
        dst = WpT;
    } else {
        int idx = bid - 2593;
        kt = idx & 15;
        n0 = (idx >> 4) * 64;
        S = W_merge; nb = n0; stride = 1024;
        dst = WmT;
    }
    {
        int kl = tid >> 2, q = tid & 3;
        const float* src = S + (size_t)(kt * 64 + kl) * stride + nb + q * 16;
#pragma unroll
        for (int j = 0; j < 4; j++) {
            float4 v = *(const float4*)(src + j * 4);
            tile[kl][q * 16 + j * 4 + 0] = v.x;
            tile[kl][q * 16 + j * 4 + 1] = v.y;
            tile[kl][q * 16 + j * 4 + 2] = v.z;
            tile[kl][q * 16 + j * 4 + 3] = v.w;
        }
    }
    __syncthreads();
    {
        int nl = tid >> 2, q = tid & 3;
        unsigned* d = (unsigned*)(dst + (size_t)(n0 + nl) * 1024 + kt * 64 + q * 16);
#pragma unroll
        for (int j = 0; j < 8; j++)
            d[j] = pk2(tile[q * 16 + j * 2][nl], tile[q * 16 + j * 2 + 1][nl]);
    }
}

// ---------------- bf16 MFMA GEMM: BM=64, BN=64, BK=128; grid (32,16) -------------------
template <bool SOFTPLUS, typename OutT>
__global__ __launch_bounds__(256) void gemm_bf16(const __hip_bfloat16* __restrict__ A,
                                                 const __hip_bfloat16* __restrict__ BT_,
                                                 const float* __restrict__ bias0,
                                                 const float* __restrict__ bias1, int N0,
                                                 OutT* __restrict__ C, int N, int K) {
    __shared__ short Ab[2][2][64 * 64];
    __shared__ short Bb[2][2][64 * 64];
    int tid = threadIdx.x, lane = tid & 63, wid = tid >> 6;
    int l15 = lane & 15, lg = lane >> 4;
    int rowblk = blockIdx.x * 64, colblk = blockIdx.y * 64;
    int wr = wid & 1, wc = wid >> 1;
    int srow = lane >> 3;
    int sk = ((lane & 7) ^ srow) * 8;

    f32x4 acc[2][2];
#pragma unroll
    for (int i = 0; i < 2; i++)
#pragma unroll
        for (int j = 0; j < 2; j++) acc[i][j] = (f32x4){0.f, 0.f, 0.f, 0.f};

    auto stage = [&](int kbase, int buf, int sub) {
#pragma unroll
        for (int j = 0; j < 2; j++) {
            int c = wid * 2 + j;
            int row = c * 8 + srow;
            lds_load16(&Ab[buf][sub][c * 512], A + (size_t)(rowblk + row) * K + kbase + sk);
            lds_load16(&Bb[buf][sub][c * 512], BT_ + (size_t)(colblk + row) * K + kbase + sk);
        }
    };
    stage(0, 0, 0);
    stage(64, 0, 1);
    __syncthreads();
    int cur = 0;
    int nks = K >> 7;   // 8
    for (int ks = 0; ks < nks; ks++) {
        if (ks + 1 < nks) {
            stage((ks + 1) << 7, cur ^ 1, 0);
            stage(((ks + 1) << 7) + 64, cur ^ 1, 1);
        }
#pragma unroll
        for (int sub = 0; sub < 2; sub++) {
#pragma unroll
            for (int kh = 0; kh < 2; kh++) {
                short8 af[2], bfr[2];
#pragma unroll
                for (int rf = 0; rf < 2; rf++) {
                    int row = wr * 32 + rf * 16 + l15;
                    int ksw = (kh * 32 + lg * 8) ^ ((row & 7) << 3);
                    af[rf] = *(const short8*)&Ab[cur][sub][row * 64 + ksw];
                }
#pragma unroll
                for (int cf = 0; cf < 2; cf++) {
                    int col = wc * 32 + cf * 16 + l15;
                    int ksw = (kh * 32 + lg * 8) ^ ((col & 7) << 3);
                    bfr[cf] = *(const short8*)&Bb[cur][sub][col * 64 + ksw];
                }
#pragma unroll
                for (int rf = 0; rf < 2; rf++)
#pragma unroll
                    for (int cf = 0; cf < 2; cf++)
                        acc[rf][cf] = __builtin_amdgcn_mfma_f32_16x16x32_bf16(
                            af[rf], bfr[cf], acc[rf][cf], 0, 0, 0);
            }
        }
        __syncthreads();
        cur ^= 1;
    }
#pragma unroll
    for (int cf = 0; cf < 2; cf++) {
        int col = colblk + wc * 32 + cf * 16 + l15;
        float bv = (col < N0) ? bias0[col] : bias1[col - N0];
#pragma unroll
        for (int rf = 0; rf < 2; rf++) {
            int rbase = rowblk + wr * 32 + rf * 16 + lg * 4;
#pragma unroll
            for (int i = 0; i < 4; i++) {
                float v = acc[rf][cf][i] + bv;
                if (SOFTPLUS) v = softplus_f(v);
                C[(size_t)(rbase + i) * N + col] = (OutT)v;
            }
        }
    }
}

// ---------------- k4: LDS-staged B, wave = 64 rows x 16 m (4 row-frags, cf=1) ----------
// num[row,m] = sum_a rq[row,a] * sum_a2 aq[row,a2] * kern2[b][a][m][a2]
__global__ __launch_bounds__(256) void k4_mfma(const _Float16* __restrict__ aqrq16,
                                               const _Float16* __restrict__ kern2,
                                               const float* __restrict__ kern_n,
                                               const float* __restrict__ norm_k,
                                               __hip_bfloat16* __restrict__ resp) {
    __shared__ _Float16 Bb[2][2][64 * 64];  // 32KB
    __shared__ _Float16 rql[64][72];        // 9.2KB
    __shared__ float scl[64];
    __shared__ float nkl[64];
    int tid = threadIdx.x, lane = tid & 63, wid = tid >> 6;
    int l15 = lane & 15, lg = lane >> 4;
    int b = blockIdx.x >> 7;
    int rc = (blockIdx.x >> 1) & 63;
    int mh = blockIdx.x & 1;
    int rowbase = rc * 64;
    float* knl = (float*)&Bb[1][0][0];      // 16KB alias, dead until first prefetch

    auto stageB = [&](int a_, int buf, int sl) {
#pragma unroll
        for (int j = 0; j < 2; j++) {
            int c = wid * 2 + j;
            int m = c * 8 + (lane >> 3);
            int sa = ((lane & 7) ^ (lane >> 3)) * 8;
            lds_load16(&Bb[buf][sl][c * 512],
                       kern2 + (((size_t)(b * 64 + a_)) * Mc + mh * 64 + m) * DAc + sa);
        }
    };
    stageB(0, 0, 0);
    stageB(1, 0, 1);
    {   // kern_n[b] -> knl (16KB, async)
#pragma unroll
        for (int j = 0; j < 4; j++) {
            int c = wid * 4 + j;
            lds_load16(knl + c * 256, kern_n + (size_t)b * 4096 + c * 256 + lane * 4);
        }
    }

    // aq fragments (loop-invariant): 4 row-frags x 2 k-halves
    half8 aqp[4][2];
#pragma unroll
    for (int rf = 0; rf < 4; rf++)
#pragma unroll
        for (int kh = 0; kh < 2; kh++) {
            int rg = rowbase + rf * 16 + l15;
            int t_ = rg >> 3, h = rg & 7;
            aqp[rf][kh] = *(const half8*)(aqrq16 + ((size_t)(b * Tc + t_)) * 1024
                                          + h * 64 + kh * 32 + lg * 8);
        }
    {   // rq rows -> LDS f16 (16 halves per thread)
        int row = tid >> 2, q = tid & 3;
        int rg = rowbase + row;
        int t_ = rg >> 3, h = rg & 7;
        const _Float16* src = aqrq16 + ((size_t)(b * Tc + t_)) * 1024 + 512 + h * 64 + q * 16;
        *(half8*)&rql[row][q * 16] = *(const half8*)(src);
        *(half8*)&rql[row][q * 16 + 8] = *(const half8*)(src + 8);
    }
    if (tid < 64) nkl[tid] = norm_k[tid];
    __syncthreads();

    // ---- scale phase: wave handles 16 rows x 4 d-chunks; knl reads broadcast ----
    {
        int row = wid * 16 + (lane >> 2);
        int c = lane & 3;
        int rg = rowbase + row;
        int t_ = rg >> 3, h = rg & 7;
        const _Float16* aqg = aqrq16 + ((size_t)(b * Tc + t_)) * 1024 + h * 64;
        float accj[16];
#pragma unroll
        for (int j = 0; j < 16; j++) accj[j] = 0.f;
        float d1 = 0.f;
#pragma unroll
        for (int a2c = 0; a2c < 4; a2c++) {
            half8 aa0 = *(const half8*)(aqg + a2c * 16);
            half8 aa1 = *(const half8*)(aqg + a2c * 16 + 8);
            float aqv[16];
#pragma unroll
            for (int j = 0; j < 8; j++) { aqv[j] = (float)aa0[j]; aqv[8 + j] = (float)aa1[j]; }
#pragma unroll
            for (int a2l = 0; a2l < 16; a2l++) {
                int a2 = a2c * 16 + a2l;
                float av = aqv[a2l];
                d1 = fmaf(av, nkl[a2], d1);
                const float4* kr = (const float4*)(knl + a2 * 64 + c * 16);
#pragma unroll
                for (int j4 = 0; j4 < 4; j4++) {
                    float4 kv = kr[j4];
                    accj[j4 * 4 + 0] = fmaf(av, kv.x, accj[j4 * 4 + 0]);
                    accj[j4 * 4 + 1] = fmaf(av, kv.y, accj[j4 * 4 + 1]);
                    accj[j4 * 4 + 2] = fmaf(av, kv.z, accj[j4 * 4 + 2]);
                    accj[j4 * 4 + 3] = fmaf(av, kv.w, accj[j4 * 4 + 3]);
                }
            }
        }
        float sn = 0.f;
#pragma unroll
        for (int j = 0; j < 16; j++)
            sn = fmaf((float)rql[row][c * 16 + j], accj[j], sn);
        sn += __shfl_xor(sn, 1);
        sn += __shfl_xor(sn, 2);
        if (c == 0) {
            float den1 = d1 + EPSF;
            float den = sn / den1 + EPSF;
            scl[row] = 1.f / (den1 * den);
        }
    }
    __syncthreads();   // scl ready; knl reads done -> Bb[1] reusable

    f32x4 acc[4];
#pragma unroll
    for (int i = 0; i < 4; i++) acc[i] = (f32x4){0.f, 0.f, 0.f, 0.f};

    int mloc = wid * 16 + l15;                  // wave owns m-chunk [wid*16, wid*16+16)
    int cur = 0;
    for (int it = 0; it < 32; it++) {
        if (it < 31) {
            stageB(it * 2 + 2, cur ^ 1, 0);
            stageB(it * 2 + 3, cur ^ 1, 1);
        }
#pragma unroll
        for (int as = 0; as < 2; as++) {
            int a = it * 2 + as;
            half8 rb[4];
#pragma unroll
            for (int rf = 0; rf < 4; rf++) {
                _Float16 hv = rql[rf * 16 + l15][a];
                rb[rf] = (half8){hv, hv, hv, hv, hv, hv, hv, hv};
            }
#pragma unroll
            for (int kh = 0; kh < 2; kh++) {
                int ch = (kh * 4 + lg) ^ (mloc & 7);
                half8 bf = *(const half8*)&Bb[cur][as][mloc * 64 + ch * 8];
#pragma unroll
                for (int rf = 0; rf < 4; rf++)
                    acc[rf] = __builtin_amdgcn_mfma_f32_16x16x32_f16(
                        aqp[rf][kh] * rb[rf], bf, acc[rf], 0, 0, 0);
            }
        }
        __syncthreads();
        cur ^= 1;
    }
#pragma unroll
    for (int rf = 0; rf < 4; rf++) {
#pragma unroll
        for (int i = 0; i < 4; i++) {
            int rl = rf * 16 + lg * 4 + i;
            int rg = rowbase + rl;
            float s = scl[rl];
            int t_ = rg >> 3, h = rg & 7;
            __hip_bfloat16* dst = resp + ((size_t)(b * Tc + t_)) * 1024 + h * DMc + mh * 64;
            dst[mloc] = __float2bfloat16(acc[rf][i] * s);
        }
    }
}

extern "C" void kernel_launch(void* const* d_in, const int* in_sizes, int n_in,
                              void* d_out, int out_size, void* d_ws, size_t ws_size,
                              hipStream_t stream) {
    const float* query      = (const float*)d_in[0];
    const float* matrix     = (const float*)d_in[1];
    const float* normalizer = (const float*)d_in[2];
    const float* addresses  = (const float*)d_in[3];
    const float* W_access   = (const float*)d_in[4];
    const float* b_access   = (const float*)d_in[5];
    const float* W_read     = (const float*)d_in[6];
    const float* b_read     = (const float*)d_in[7];
    const float* W_merge    = (const float*)d_in[8];
    const float* b_merge    = (const float*)d_in[9];
    float* out = (float*)d_out;
    (void)in_sizes; (void)n_in; (void)out_size; (void)ws_size;

    float* ws     = (float*)d_ws;
    float* norm_k = ws;                        // 64 (+pad to 128)
    float* kern_n = ws + 128;                  // 16384
    _Float16* aqrq16 = (_Float16*)(ws + 16512);               // 2,097,152 f16
    _Float16* kern2  = (_Float16*)(ws + 1065088);             // 2,097,152 f16
    __hip_bfloat16* qb   = (__hip_bfloat16*)(ws + 2113664);   // 2,097,152 bf16
    __hip_bfloat16* resp = (__hip_bfloat16*)(ws + 3162240);   // 2,097,152 bf16
    __hip_bfloat16* WpT  = (__hip_bfloat16*)(ws + 4210816);   // 1,048,576 bf16
    __hip_bfloat16* WmT  = (__hip_bfloat16*)(ws + 4735104);   // 1,048,576 bf16
    // total 5,259,392 floats = 21.0 MB

    hipLaunchKernelGGL(front_kern, dim3(2849), dim3(256), 0, stream,
                       addresses, matrix, normalizer, query,
                       W_access, W_read, W_merge,
                       kern2, kern_n, norm_k, qb, WpT, WmT);
    hipLaunchKernelGGL((gemm_bf16<true, _Float16>), dim3(32, 16), dim3(256), 0, stream,
                       qb, WpT, b_access, b_read, 512, aqrq16, 1024, 1024);
    hipLaunchKernelGGL(k4_mfma, dim3(512), dim3(256), 0, stream,
                       aqrq16, kern2, kern_n, norm_k, resp);
    hipLaunchKernelGGL((gemm_bf16<false, float>), dim3(32, 16), dim3(256), 0, stream,
                       resp, WmT, b_merge, b_merge, 2048, out, 1024, 1024);
}

// Round 15
// 89.571 us; speedup vs baseline: 1.3833x; 1.0553x over previous
//
#include <hip/hip_runtime.h>
#include <hip/hip_bf16.h>
#include <math.h>

#define EPSF 1e-5f

typedef __attribute__((ext_vector_type(8))) short short8;
typedef __attribute__((ext_vector_type(4))) float f32x4;
typedef _Float16 half8 __attribute__((ext_vector_type(8)));

constexpr int Bc = 4, Tc = 512, Dc = 1024, Mc = 128, Hc = 8, DAc = 64, DMc = 128;
constexpr int BT = Bc * Tc;      // 2048
constexpr int Xc = DAc * DMc;    // 8192
constexpr int Rb = Tc * Hc;      // 4096 rows per batch (t*8+h)

__device__ __forceinline__ float softplus_f(float x) {
    return fmaxf(x, 0.f) + log1pf(expf(-fabsf(x)));
}
__device__ __forceinline__ short f2bf(float f) {
    __hip_bfloat16 h = __float2bfloat16(f);
    return *reinterpret_cast<short*>(&h);
}
__device__ __forceinline__ unsigned pk2(float a, float b) {
    return (unsigned)(unsigned short)f2bf(a) | ((unsigned)(unsigned short)f2bf(b) << 16);
}
// async global->LDS, 16B per lane; lds base must be wave-uniform
__device__ __forceinline__ void lds_load16(void* lds, const void* g) {
    __builtin_amdgcn_global_load_lds((const __attribute__((address_space(1))) int*)g,
                                     (__attribute__((address_space(3))) int*)lds, 16, 0, 0);
}

// ---------------- front: k1t | k2 | norm_k | convq | tW --------------------------------
__global__ __launch_bounds__(256) void front_kern(
        const float* __restrict__ addresses,
        const float* __restrict__ matrix,
        const float* __restrict__ normalizer,
        const float* __restrict__ query,
        const float* __restrict__ W_access,
        const float* __restrict__ W_read,
        const float* __restrict__ W_merge,
        _Float16* __restrict__ kern2,
        float* __restrict__ kern_n,
        float* __restrict__ norm_k,
        __hip_bfloat16* __restrict__ qb,
        __hip_bfloat16* __restrict__ WpT,
        __hip_bfloat16* __restrict__ WmT) {
    __shared__ float smem[8192];   // 32KB, carved per branch
    int bid = blockIdx.x;
    int tid = threadIdx.x;

    if (bid < 256) {
        // ---- k1t: kern2[b][a][m][a2] = sum_mm matrix[b][mm][a][m]*softplus(addr[mm][a2])
        float (*T)[132] = (float(*)[132])smem;
        _Float16 (*At)[40] = (_Float16(*)[40])(smem + 4224);
        int lane = tid & 63, wid = tid >> 6;
        int l15 = lane & 15, lg = lane >> 4;
        int b = bid >> 6, a = bid & 63;
        int wr = wid & 1, wc = wid >> 1;

        half8 bfrag[2][4];
#pragma unroll
        for (int cf = 0; cf < 2; cf++) {
            int a2 = wc * 32 + cf * 16 + l15;
#pragma unroll
            for (int ks = 0; ks < 4; ks++)
#pragma unroll
                for (int j = 0; j < 8; j++) {
                    int mm = ks * 32 + lg * 8 + j;
                    bfrag[cf][ks][j] = (_Float16)softplus_f(addresses[mm * 64 + a2]);
                }
        }

        const float* msrc = matrix + (size_t)b * Mc * Xc + a * DMc;
        int r = tid >> 3, ms = (tid & 7) * 16;
        int tm = tid >> 1, tk0 = (tid & 1) * 16;

        f32x4 acc[4][2];
#pragma unroll
        for (int i = 0; i < 4; i++)
#pragma unroll
            for (int j = 0; j < 2; j++) acc[i][j] = (f32x4){0.f, 0.f, 0.f, 0.f};

        float4 ld[4];
#pragma unroll
        for (int j = 0; j < 4; j++)
            ld[j] = *(const float4*)(msrc + (size_t)r * Xc + ms + j * 4);

        for (int s = 0; s < 4; s++) {
#pragma unroll
            for (int j = 0; j < 4; j++) *(float4*)&T[r][ms + j * 4] = ld[j];
            __syncthreads();
            if (s < 3) {
#pragma unroll
                for (int j = 0; j < 4; j++)
                    ld[j] = *(const float4*)(msrc + (size_t)((s + 1) * 32 + r) * Xc + ms + j * 4);
            }
            {
                half8 lo, hi;
#pragma unroll
                for (int j = 0; j < 8; j++) lo[j] = (_Float16)T[tk0 + j][tm];
#pragma unroll
                for (int j = 0; j < 8; j++) hi[j] = (_Float16)T[tk0 + 8 + j][tm];
                *(half8*)&At[tm][tk0] = lo;
                *(half8*)&At[tm][tk0 + 8] = hi;
            }
            __syncthreads();
#pragma unroll
            for (int rf = 0; rf < 4; rf++) {
                int row = wr * 64 + rf * 16 + l15;
                half8 af = *(const half8*)&At[row][lg * 8];
#pragma unroll
                for (int cf = 0; cf < 2; cf++)
                    acc[rf][cf] = __builtin_amdgcn_mfma_f32_16x16x32_f16(
                        af, bfrag[cf][s], acc[rf][cf], 0, 0, 0);
            }
            __syncthreads();
        }
        _Float16* dst = kern2 + ((size_t)(b * 64 + a)) * Mc * DAc;
#pragma unroll
        for (int rf = 0; rf < 4; rf++)
#pragma unroll
            for (int cf = 0; cf < 2; cf++) {
                int a2 = wc * 32 + cf * 16 + l15;
#pragma unroll
                for (int i = 0; i < 4; i++) {
                    int mrow = wr * 64 + rf * 16 + lg * 4 + i;
                    dst[mrow * DAc + a2] = (_Float16)acc[rf][cf][i];
                }
            }
        return;
    }
    if (bid < 288) {
        // ---- k2
        int idx = bid - 256;
        int b = idx >> 3, ch = idx & 7;
        for (int i = tid; i < Mc * DAc; i += 256) smem[i] = softplus_f(addresses[i]);
        __syncthreads();
        int d = tid & 63;
        int g = tid >> 6;
        int a2b = ch * 8 + g * 2;
        float acc0 = 0.f, acc1 = 0.f;
        const float* np = normalizer + (size_t)b * Mc * DAc + d;
        for (int mm = 0; mm < Mc; mm++) {
            float v = np[(size_t)mm * DAc];
            acc0 = fmaf(smem[mm * DAc + a2b + 0], v, acc0);
            acc1 = fmaf(smem[mm * DAc + a2b + 1], v, acc1);
        }
        kern_n[((size_t)b * DAc + a2b + 0) * DAc + d] = acc0;
        kern_n[((size_t)b * DAc + a2b + 1) * DAc + d] = acc1;
        return;
    }
    if (bid == 288) {
        // ---- norm_k
        for (int i = tid; i < Mc * DAc; i += 256) smem[i] = softplus_f(addresses[i]);
        __syncthreads();
        if (tid < DAc) {
            float s = 0.f;
            for (int mm = 0; mm < Mc; mm++) s += smem[mm * DAc + tid];
            norm_k[tid] = s;
        }
        return;
    }
    if (bid < 2337) {
        // ---- convq
        int i = ((bid - 289) * 256 + tid) * 4;
        float4 v = *(const float4*)(query + i);
        unsigned* d = (unsigned*)(qb + i);
        d[0] = pk2(v.x, v.y);
        d[1] = pk2(v.z, v.w);
        return;
    }
    // ---- tW
    float (*tile)[65] = (float(*)[65])smem;
    const float* S; int stride, nb, n0, kt;
    __hip_bfloat16* dst;
    if (bid < 2593) {
        int idx = bid - 2337;
        kt = idx & 15;
        n0 = (idx >> 4) * 64;
        if (n0 < 512) { S = W_access; nb = n0; }
        else          { S = W_read;   nb = n0 - 512; }
        stride = 512;
        dst = WpT;
    } else {
        int idx = bid - 2593;
        kt = idx & 15;
        n0 = (idx >> 4) * 64;
        S = W_merge; nb = n0; stride = 1024;
        dst = WmT;
    }
    {
        int kl = tid >> 2, q = tid & 3;
        const float* src = S + (size_t)(kt * 64 + kl) * stride + nb + q * 16;
#pragma unroll
        for (int j = 0; j < 4; j++) {
            float4 v = *(const float4*)(src + j * 4);
            tile[kl][q * 16 + j * 4 + 0] = v.x;
            tile[kl][q * 16 + j * 4 + 1] = v.y;
            tile[kl][q * 16 + j * 4 + 2] = v.z;
            tile[kl][q * 16 + j * 4 + 3] = v.w;
        }
    }
    __syncthreads();
    {
        int nl = tid >> 2, q = tid & 3;
        unsigned* d = (unsigned*)(dst + (size_t)(n0 + nl) * 1024 + kt * 64 + q * 16);
#pragma unroll
        for (int j = 0; j < 8; j++)
            d[j] = pk2(tile[q * 16 + j * 2][nl], tile[q * 16 + j * 2 + 1][nl]);
    }
}

// ---------------- bf16 MFMA GEMM: BM=64, BN=64, BK=128; grid (32,16) -------------------
template <bool SOFTPLUS, typename OutT>
__global__ __launch_bounds__(256) void gemm_bf16(const __hip_bfloat16* __restrict__ A,
                                                 const __hip_bfloat16* __restrict__ BT_,
                                                 const float* __restrict__ bias0,
                                                 const float* __restrict__ bias1, int N0,
                                                 OutT* __restrict__ C, int N, int K) {
    __shared__ short Ab[2][2][64 * 64];
    __shared__ short Bb[2][2][64 * 64];
    int tid = threadIdx.x, lane = tid & 63, wid = tid >> 6;
    int l15 = lane & 15, lg = lane >> 4;
    int rowblk = blockIdx.x * 64, colblk = blockIdx.y * 64;
    int wr = wid & 1, wc = wid >> 1;
    int srow = lane >> 3;
    int sk = ((lane & 7) ^ srow) * 8;

    f32x4 acc[2][2];
#pragma unroll
    for (int i = 0; i < 2; i++)
#pragma unroll
        for (int j = 0; j < 2; j++) acc[i][j] = (f32x4){0.f, 0.f, 0.f, 0.f};

    auto stage = [&](int kbase, int buf, int sub) {
#pragma unroll
        for (int j = 0; j < 2; j++) {
            int c = wid * 2 + j;
            int row = c * 8 + srow;
            lds_load16(&Ab[buf][sub][c * 512], A + (size_t)(rowblk + row) * K + kbase + sk);
            lds_load16(&Bb[buf][sub][c * 512], BT_ + (size_t)(colblk + row) * K + kbase + sk);
        }
    };
    stage(0, 0, 0);
    stage(64, 0, 1);
    __syncthreads();
    int cur = 0;
    int nks = K >> 7;   // 8
    for (int ks = 0; ks < nks; ks++) {
        if (ks + 1 < nks) {
            stage((ks + 1) << 7, cur ^ 1, 0);
            stage(((ks + 1) << 7) + 64, cur ^ 1, 1);
        }
#pragma unroll
        for (int sub = 0; sub < 2; sub++) {
#pragma unroll
            for (int kh = 0; kh < 2; kh++) {
                short8 af[2], bfr[2];
#pragma unroll
                for (int rf = 0; rf < 2; rf++) {
                    int row = wr * 32 + rf * 16 + l15;
                    int ksw = (kh * 32 + lg * 8) ^ ((row & 7) << 3);
                    af[rf] = *(const short8*)&Ab[cur][sub][row * 64 + ksw];
                }
#pragma unroll
                for (int cf = 0; cf < 2; cf++) {
                    int col = wc * 32 + cf * 16 + l15;
                    int ksw = (kh * 32 + lg * 8) ^ ((col & 7) << 3);
                    bfr[cf] = *(const short8*)&Bb[cur][sub][col * 64 + ksw];
                }
#pragma unroll
                for (int rf = 0; rf < 2; rf++)
#pragma unroll
                    for (int cf = 0; cf < 2; cf++)
                        acc[rf][cf] = __builtin_amdgcn_mfma_f32_16x16x32_bf16(
                            af[rf], bfr[cf], acc[rf][cf], 0, 0, 0);
            }
        }
        __syncthreads();
        cur ^= 1;
    }
#pragma unroll
    for (int cf = 0; cf < 2; cf++) {
        int col = colblk + wc * 32 + cf * 16 + l15;
        float bv = (col < N0) ? bias0[col] : bias1[col - N0];
#pragma unroll
        for (int rf = 0; rf < 2; rf++) {
            int rbase = rowblk + wr * 32 + rf * 16 + lg * 4;
#pragma unroll
            for (int i = 0; i < 4; i++) {
                float v = acc[rf][cf][i] + bv;
                if (SOFTPLUS) v = softplus_f(v);
                C[(size_t)(rbase + i) * N + col] = (OutT)v;
            }
        }
    }
}

// ---------------- k4: per-wave-private B strips -> barrier-free counted-vmcnt loop -----
// wave w stages AND consumes only m-strip [w*16, w*16+16) => no inter-wave barrier needed.
// vmcnt accounting: issue BOTH next-pair stages (8 outstanding), then vmcnt(4) retires
// exactly the current pair's 4 loads. Tail: vmcnt(0).
__global__ __launch_bounds__(256) void k4_mfma(const _Float16* __restrict__ aqrq16,
                                               const _Float16* __restrict__ kern2,
                                               const float* __restrict__ kern_n,
                                               const float* __restrict__ norm_k,
                                               __hip_bfloat16* __restrict__ resp) {
    __shared__ _Float16 Bb[2][2][64 * 64];  // 32KB
    __shared__ _Float16 rql[64][72];        // 9.2KB
    __shared__ float scl[64];
    __shared__ float nkl[64];
    int tid = threadIdx.x, lane = tid & 63, wid = tid >> 6;
    int l15 = lane & 15, lg = lane >> 4;
    int b = blockIdx.x >> 7;
    int rc = (blockIdx.x >> 1) & 63;
    int mh = blockIdx.x & 1;
    int rowbase = rc * 64;
    float* knl = (float*)&Bb[1][0][0];      // 16KB alias, dead after scale phase

    auto stageB = [&](int a_, int buf, int sl) {
#pragma unroll
        for (int j = 0; j < 2; j++) {
            int c = wid * 2 + j;
            int m = c * 8 + (lane >> 3);
            int sa = ((lane & 7) ^ (lane >> 3)) * 8;
            lds_load16(&Bb[buf][sl][c * 512],
                       kern2 + (((size_t)(b * 64 + a_)) * Mc + mh * 64 + m) * DAc + sa);
        }
    };
    stageB(0, 0, 0);
    stageB(1, 0, 1);
    {   // kern_n[b] -> knl (16KB, async)
#pragma unroll
        for (int j = 0; j < 4; j++) {
            int c = wid * 4 + j;
            lds_load16(knl + c * 256, kern_n + (size_t)b * 4096 + c * 256 + lane * 4);
        }
    }

    // aq fragments (loop-invariant): 4 row-frags x 2 k-halves
    half8 aqp[4][2];
#pragma unroll
    for (int rf = 0; rf < 4; rf++)
#pragma unroll
        for (int kh = 0; kh < 2; kh++) {
            int rg = rowbase + rf * 16 + l15;
            int t_ = rg >> 3, h = rg & 7;
            aqp[rf][kh] = *(const half8*)(aqrq16 + ((size_t)(b * Tc + t_)) * 1024
                                          + h * 64 + kh * 32 + lg * 8);
        }
    {   // rq rows -> LDS f16 (16 halves per thread)
        int row = tid >> 2, q = tid & 3;
        int rg = rowbase + row;
        int t_ = rg >> 3, h = rg & 7;
        const _Float16* src = aqrq16 + ((size_t)(b * Tc + t_)) * 1024 + 512 + h * 64 + q * 16;
        *(half8*)&rql[row][q * 16] = *(const half8*)(src);
        *(half8*)&rql[row][q * 16 + 8] = *(const half8*)(src + 8);
    }
    if (tid < 64) nkl[tid] = norm_k[tid];
    __syncthreads();

    // ---- scale phase: wave handles 16 rows x 4 d-chunks; knl reads broadcast ----
    {
        int row = wid * 16 + (lane >> 2);
        int c = lane & 3;
        int rg = rowbase + row;
        int t_ = rg >> 3, h = rg & 7;
        const _Float16* aqg = aqrq16 + ((size_t)(b * Tc + t_)) * 1024 + h * 64;
        float accj[16];
#pragma unroll
        for (int j = 0; j < 16; j++) accj[j] = 0.f;
        float d1 = 0.f;
#pragma unroll
        for (int a2c = 0; a2c < 4; a2c++) {
            half8 aa0 = *(const half8*)(aqg + a2c * 16);
            half8 aa1 = *(const half8*)(aqg + a2c * 16 + 8);
            float aqv[16];
#pragma unroll
            for (int j = 0; j < 8; j++) { aqv[j] = (float)aa0[j]; aqv[8 + j] = (float)aa1[j]; }
#pragma unroll
            for (int a2l = 0; a2l < 16; a2l++) {
                int a2 = a2c * 16 + a2l;
                float av = aqv[a2l];
                d1 = fmaf(av, nkl[a2], d1);
                const float4* kr = (const float4*)(knl + a2 * 64 + c * 16);
#pragma unroll
                for (int j4 = 0; j4 < 4; j4++) {
                    float4 kv = kr[j4];
                    accj[j4 * 4 + 0] = fmaf(av, kv.x, accj[j4 * 4 + 0]);
                    accj[j4 * 4 + 1] = fmaf(av, kv.y, accj[j4 * 4 + 1]);
                    accj[j4 * 4 + 2] = fmaf(av, kv.z, accj[j4 * 4 + 2]);
                    accj[j4 * 4 + 3] = fmaf(av, kv.w, accj[j4 * 4 + 3]);
                }
            }
        }
        float sn = 0.f;
#pragma unroll
        for (int j = 0; j < 16; j++)
            sn = fmaf((float)rql[row][c * 16 + j], accj[j], sn);
        sn += __shfl_xor(sn, 1);
        sn += __shfl_xor(sn, 2);
        if (c == 0) {
            float den1 = d1 + EPSF;
            float den = sn / den1 + EPSF;
            scl[row] = 1.f / (den1 * den);
        }
    }
    __syncthreads();   // scl ready; knl dead; all prologue staging drained (vmcnt 0)

    f32x4 acc[4];
#pragma unroll
    for (int i = 0; i < 4; i++) acc[i] = (f32x4){0.f, 0.f, 0.f, 0.f};

    int mloc = wid * 16 + l15;                  // wave owns m-chunk [wid*16, wid*16+16)
    int cur = 0;
    for (int it = 0; it < 32; it++) {
        if (it < 31) {
            stageB(it * 2 + 2, cur ^ 1, 0);     // +2 per thread
            stageB(it * 2 + 3, cur ^ 1, 1);     // +2 -> 8 outstanding in steady state
            asm volatile("s_waitcnt vmcnt(4)" ::: "memory");  // current pair's 4 retired
        } else {
            asm volatile("s_waitcnt vmcnt(0)" ::: "memory");
        }
        __builtin_amdgcn_sched_barrier(0);
#pragma unroll
        for (int as = 0; as < 2; as++) {
            int a = it * 2 + as;
            half8 rb[4];
#pragma unroll
            for (int rf = 0; rf < 4; rf++) {
                _Float16 hv = rql[rf * 16 + l15][a];
                rb[rf] = (half8){hv, hv, hv, hv, hv, hv, hv, hv};
            }
#pragma unroll
            for (int kh = 0; kh < 2; kh++) {
                int ch = (kh * 4 + lg) ^ (mloc & 7);
                half8 bf = *(const half8*)&Bb[cur][as][mloc * 64 + ch * 8];
#pragma unroll
                for (int rf = 0; rf < 4; rf++)
                    acc[rf] = __builtin_amdgcn_mfma_f32_16x16x32_f16(
                        aqp[rf][kh] * rb[rf], bf, acc[rf], 0, 0, 0);
            }
        }
        cur ^= 1;
    }
#pragma unroll
    for (int rf = 0; rf < 4; rf++) {
#pragma unroll
        for (int i = 0; i < 4; i++) {
            int rl = rf * 16 + lg * 4 + i;
            int rg = rowbase + rl;
            float s = scl[rl];
            int t_ = rg >> 3, h = rg & 7;
            __hip_bfloat16* dst = resp + ((size_t)(b * Tc + t_)) * 1024 + h * DMc + mh * 64;
            dst[mloc] = __float2bfloat16(acc[rf][i] * s);
        }
    }
}

extern "C" void kernel_launch(void* const* d_in, const int* in_sizes, int n_in,
                              void* d_out, int out_size, void* d_ws, size_t ws_size,
                              hipStream_t stream) {
    const float* query      = (const float*)d_in[0];
    const float* matrix     = (const float*)d_in[1];
    const float* normalizer = (const float*)d_in[2];
    const float* addresses  = (const float*)d_in[3];
    const float* W_access   = (const float*)d_in[4];
    const float* b_access   = (const float*)d_in[5];
    const float* W_read     = (const float*)d_in[6];
    const float* b_read     = (const float*)d_in[7];
    const float* W_merge    = (const float*)d_in[8];
    const float* b_merge    = (const float*)d_in[9];
    float* out = (float*)d_out;
    (void)in_sizes; (void)n_in; (void)out_size; (void)ws_size;

    float* ws     = (float*)d_ws;
    float* norm_k = ws;                        // 64 (+pad to 128)
    float* kern_n = ws + 128;                  // 16384
    _Float16* aqrq16 = (_Float16*)(ws + 16512);               // 2,097,152 f16
    _Float16* kern2  = (_Float16*)(ws + 1065088);             // 2,097,152 f16
    __hip_bfloat16* qb   = (__hip_bfloat16*)(ws + 2113664);   // 2,097,152 bf16
    __hip_bfloat16* resp = (__hip_bfloat16*)(ws + 3162240);   // 2,097,152 bf16
    __hip_bfloat16* WpT  = (__hip_bfloat16*)(ws + 4210816);   // 1,048,576 bf16
    __hip_bfloat16* WmT  = (__hip_bfloat16*)(ws + 4735104);   // 1,048,576 bf16
    // total 5,259,392 floats = 21.0 MB

    hipLaunchKernelGGL(front_kern, dim3(2849), dim3(256), 0, stream,
                       addresses, matrix, normalizer, query,
                       W_access, W_read, W_merge,
                       kern2, kern_n, norm_k, qb, WpT, WmT);
    hipLaunchKernelGGL((gemm_bf16<true, _Float16>), dim3(32, 16), dim3(256), 0, stream,
                       qb, WpT, b_access, b_read, 512, aqrq16, 1024, 1024);
    hipLaunchKernelGGL(k4_mfma, dim3(512), dim3(256), 0, stream,
                       aqrq16, kern2, kern_n, norm_k, resp);
    hipLaunchKernelGGL((gemm_bf16<false, float>), dim3(32, 16), dim3(256), 0, stream,
                       resp, WmT, b_merge, b_merge, 2048, out, 1024, 1024);
}

// Round 19
// 88.519 us; speedup vs baseline: 1.3998x; 1.0119x over previous
//
#include <hip/hip_runtime.h>
#include <hip/hip_bf16.h>
#include <math.h>

#define EPSF 1e-5f

typedef __attribute__((ext_vector_type(8))) short short8;
typedef __attribute__((ext_vector_type(4))) float f32x4;
typedef _Float16 half8 __attribute__((ext_vector_type(8)));

constexpr int Bc = 4, Tc = 512, Dc = 1024, Mc = 128, Hc = 8, DAc = 64, DMc = 128;
constexpr int BT = Bc * Tc;      // 2048
constexpr int Xc = DAc * DMc;    // 8192
constexpr int Rb = Tc * Hc;      // 4096 rows per batch (t*8+h)

__device__ __forceinline__ float softplus_f(float x) {
    return fmaxf(x, 0.f) + log1pf(expf(-fabsf(x)));
}
__device__ __forceinline__ short f2bf(float f) {
    __hip_bfloat16 h = __float2bfloat16(f);
    return *reinterpret_cast<short*>(&h);
}
__device__ __forceinline__ unsigned pk2(float a, float b) {
    return (unsigned)(unsigned short)f2bf(a) | ((unsigned)(unsigned short)f2bf(b) << 16);
}
// async global->LDS, 16B per lane; lds base must be wave-uniform
__device__ __forceinline__ void lds_load16(void* lds, const void* g) {
    __builtin_amdgcn_global_load_lds((const __attribute__((address_space(1))) int*)g,
                                     (__attribute__((address_space(3))) int*)lds, 16, 0, 0);
}

// ---------------- front: k1t | k2 | norm_k | convq | tW --------------------------------
__global__ __launch_bounds__(256) void front_kern(
        const float* __restrict__ addresses,
        const float* __restrict__ matrix,
        const float* __restrict__ normalizer,
        const float* __restrict__ query,
        const float* __restrict__ W_access,
        const float* __restrict__ W_read,
        const float* __restrict__ W_merge,
        _Float16* __restrict__ kern2,
        float* __restrict__ kern_n,
        float* __restrict__ norm_k,
        __hip_bfloat16* __restrict__ qb,
        __hip_bfloat16* __restrict__ WpT,
        __hip_bfloat16* __restrict__ WmT) {
    __shared__ float smem[8192];   // 32KB, carved per branch
    int bid = blockIdx.x;
    int tid = threadIdx.x;

    if (bid < 256) {
        // ---- k1t: kern2[b][a][m][a2] = sum_mm matrix[b][mm][a][m]*softplus(addr[mm][a2])
        float (*T)[132] = (float(*)[132])smem;
        _Float16 (*At)[40] = (_Float16(*)[40])(smem + 4224);
        int lane = tid & 63, wid = tid >> 6;
        int l15 = lane & 15, lg = lane >> 4;
        int b = bid >> 6, a = bid & 63;
        int wr = wid & 1, wc = wid >> 1;

        half8 bfrag[2][4];
#pragma unroll
        for (int cf = 0; cf < 2; cf++) {
            int a2 = wc * 32 + cf * 16 + l15;
#pragma unroll
            for (int ks = 0; ks < 4; ks++)
#pragma unroll
                for (int j = 0; j < 8; j++) {
                    int mm = ks * 32 + lg * 8 + j;
                    bfrag[cf][ks][j] = (_Float16)softplus_f(addresses[mm * 64 + a2]);
                }
        }

        const float* msrc = matrix + (size_t)b * Mc * Xc + a * DMc;
        int r = tid >> 3, ms = (tid & 7) * 16;
        int tm = tid >> 1, tk0 = (tid & 1) * 16;

        f32x4 acc[4][2];
#pragma unroll
        for (int i = 0; i < 4; i++)
#pragma unroll
            for (int j = 0; j < 2; j++) acc[i][j] = (f32x4){0.f, 0.f, 0.f, 0.f};

        float4 ld[4];
#pragma unroll
        for (int j = 0; j < 4; j++)
            ld[j] = *(const float4*)(msrc + (size_t)r * Xc + ms + j * 4);

        for (int s = 0; s < 4; s++) {
#pragma unroll
            for (int j = 0; j < 4; j++) *(float4*)&T[r][ms + j * 4] = ld[j];
            __syncthreads();
            if (s < 3) {
#pragma unroll
                for (int j = 0; j < 4; j++)
                    ld[j] = *(const float4*)(msrc + (size_t)((s + 1) * 32 + r) * Xc + ms + j * 4);
            }
            {
                half8 lo, hi;
#pragma unroll
                for (int j = 0; j < 8; j++) lo[j] = (_Float16)T[tk0 + j][tm];
#pragma unroll
                for (int j = 0; j < 8; j++) hi[j] = (_Float16)T[tk0 + 8 + j][tm];
                *(half8*)&At[tm][tk0] = lo;
                *(half8*)&At[tm][tk0 + 8] = hi;
            }
            __syncthreads();
#pragma unroll
            for (int rf = 0; rf < 4; rf++) {
                int row = wr * 64 + rf * 16 + l15;
                half8 af = *(const half8*)&At[row][lg * 8];
#pragma unroll
                for (int cf = 0; cf < 2; cf++)
                    acc[rf][cf] = __builtin_amdgcn_mfma_f32_16x16x32_f16(
                        af, bfrag[cf][s], acc[rf][cf], 0, 0, 0);
            }
            __syncthreads();
        }
        _Float16* dst = kern2 + ((size_t)(b * 64 + a)) * Mc * DAc;
#pragma unroll
        for (int rf = 0; rf < 4; rf++)
#pragma unroll
            for (int cf = 0; cf < 2; cf++) {
                int a2 = wc * 32 + cf * 16 + l15;
#pragma unroll
                for (int i = 0; i < 4; i++) {
                    int mrow = wr * 64 + rf * 16 + lg * 4 + i;
                    dst[mrow * DAc + a2] = (_Float16)acc[rf][cf][i];
                }
            }
        return;
    }
    if (bid < 288) {
        // ---- k2
        int idx = bid - 256;
        int b = idx >> 3, ch = idx & 7;
        for (int i = tid; i < Mc * DAc; i += 256) smem[i] = softplus_f(addresses[i]);
        __syncthreads();
        int d = tid & 63;
        int g = tid >> 6;
        int a2b = ch * 8 + g * 2;
        float acc0 = 0.f, acc1 = 0.f;
        const float* np = normalizer + (size_t)b * Mc * DAc + d;
        for (int mm = 0; mm < Mc; mm++) {
            float v = np[(size_t)mm * DAc];
            acc0 = fmaf(smem[mm * DAc + a2b + 0], v, acc0);
            acc1 = fmaf(smem[mm * DAc + a2b + 1], v, acc1);
        }
        kern_n[((size_t)b * DAc + a2b + 0) * DAc + d] = acc0;
        kern_n[((size_t)b * DAc + a2b + 1) * DAc + d] = acc1;
        return;
    }
    if (bid == 288) {
        // ---- norm_k
        for (int i = tid; i < Mc * DAc; i += 256) smem[i] = softplus_f(addresses[i]);
        __syncthreads();
        if (tid < DAc) {
            float s = 0.f;
            for (int mm = 0; mm < Mc; mm++) s += smem[mm * DAc + tid];
            norm_k[tid] = s;
        }
        return;
    }
    if (bid < 2337) {
        // ---- convq
        int i = ((bid - 289) * 256 + tid) * 4;
        float4 v = *(const float4*)(query + i);
        unsigned* d = (unsigned*)(qb + i);
        d[0] = pk2(v.x, v.y);
        d[1] = pk2(v.z, v.w);
        return;
    }
    // ---- tW
    float (*tile)[65] = (float(*)[65])smem;
    const float* S; int stride, nb, n0, kt;
    __hip_bfloat16* dst;
    if (bid < 2593) {
        int idx = bid - 2337;
        kt = idx & 15;
        n0 = (idx >> 4) * 64;
        if (n0 < 512) { S = W_access; nb = n0; }
        else          { S = W_read;   nb = n0 - 512; }
        stride = 512;
        dst = WpT;
    } else {
        int idx = bid - 2593;
        kt = idx & 15;
        n0 = (idx >> 4) * 64;
        S = W_merge; nb = n0; stride = 1024;
        dst = WmT;
    }
    {
        int kl = tid >> 2, q = tid & 3;
        const float* src = S + (size_t)(kt * 64 + kl) * stride + nb + q * 16;
#pragma unroll
        for (int j = 0; j < 4; j++) {
            float4 v = *(const float4*)(src + j * 4);
            tile[kl][q * 16 + j * 4 + 0] = v.x;
            tile[kl][q * 16 + j * 4 + 1] = v.y;
            tile[kl][q * 16 + j * 4 + 2] = v.z;
            tile[kl][q * 16 + j * 4 + 3] = v.w;
        }
    }
    __syncthreads();
    {
        int nl = tid >> 2, q = tid & 3;
        unsigned* d = (unsigned*)(dst + (size_t)(n0 + nl) * 1024 + kt * 64 + q * 16);
#pragma unroll
        for (int j = 0; j < 8; j++)
            d[j] = pk2(tile[q * 16 + j * 2][nl], tile[q * 16 + j * 2 + 1][nl]);
    }
}

// ---------------- bf16 MFMA GEMM: BM=64, BN=64, BK=128; counted-vmcnt 2-barrier loop ---
template <bool SOFTPLUS, typename OutT>
__global__ __launch_bounds__(256) void gemm_bf16(const __hip_bfloat16* __restrict__ A,
                                                 const __hip_bfloat16* __restrict__ BT_,
                                                 const float* __restrict__ bias0,
                                                 const float* __restrict__ bias1, int N0,
                                                 OutT* __restrict__ C, int N, int K) {
    __shared__ short Ab[2][2][64 * 64];
    __shared__ short Bb[2][2][64 * 64];
    int tid = threadIdx.x, lane = tid & 63, wid = tid >> 6;
    int l15 = lane & 15, lg = lane >> 4;
    int rowblk = blockIdx.x * 64, colblk = blockIdx.y * 64;
    int wr = wid & 1, wc = wid >> 1;
    int srow = lane >> 3;
    int sk = ((lane & 7) ^ srow) * 8;

    f32x4 acc[2][2];
#pragma unroll
    for (int i = 0; i < 2; i++)
#pragma unroll
        for (int j = 0; j < 2; j++) acc[i][j] = (f32x4){0.f, 0.f, 0.f, 0.f};

    auto stage = [&](int kbase, int buf, int sub) {
#pragma unroll
        for (int j = 0; j < 2; j++) {
            int c = wid * 2 + j;
            int row = c * 8 + srow;
            lds_load16(&Ab[buf][sub][c * 512], A + (size_t)(rowblk + row) * K + kbase + sk);
            lds_load16(&Bb[buf][sub][c * 512], BT_ + (size_t)(colblk + row) * K + kbase + sk);
        }
    };
    stage(0, 0, 0);
    stage(64, 0, 1);      // 8 loads outstanding per thread
    int cur = 0;
    int nks = K >> 7;     // 8
    for (int ks = 0; ks < nks; ks++) {
        if (ks + 1 < nks) {
            stage((ks + 1) << 7, cur ^ 1, 0);
            stage(((ks + 1) << 7) + 64, cur ^ 1, 1);   // +8 -> 16 outstanding
            asm volatile("s_waitcnt vmcnt(8)" ::: "memory");  // current buf's 8 retired
        } else {
            asm volatile("s_waitcnt vmcnt(0)" ::: "memory");
        }
        __builtin_amdgcn_sched_barrier(0);
        __builtin_amdgcn_s_barrier();     // all waves' cur stages visible (no vmcnt0 drain)
#pragma unroll
        for (int sub = 0; sub < 2; sub++) {
#pragma unroll
            for (int kh = 0; kh < 2; kh++) {
                short8 af[2], bfr[2];
#pragma unroll
                for (int rf = 0; rf < 2; rf++) {
                    int row = wr * 32 + rf * 16 + l15;
                    int ksw = (kh * 32 + lg * 8) ^ ((row & 7) << 3);
                    af[rf] = *(const short8*)&Ab[cur][sub][row * 64 + ksw];
                }
#pragma unroll
                for (int cf = 0; cf < 2; cf++) {
                    int col = wc * 32 + cf * 16 + l15;
                    int ksw = (kh * 32 + lg * 8) ^ ((col & 7) << 3);
                    bfr[cf] = *(const short8*)&Bb[cur][sub][col * 64 + ksw];
                }
#pragma unroll
                for (int rf = 0; rf < 2; rf++)
#pragma unroll
                    for (int cf = 0; cf < 2; cf++)
                        acc[rf][cf] = __builtin_amdgcn_mfma_f32_16x16x32_bf16(
                            af[rf], bfr[cf], acc[rf][cf], 0, 0, 0);
            }
        }
        __builtin_amdgcn_s_barrier();     // all waves done reading cur -> safe to overwrite
        cur ^= 1;
    }
#pragma unroll
    for (int cf = 0; cf < 2; cf++) {
        int col = colblk + wc * 32 + cf * 16 + l15;
        float bv = (col < N0) ? bias0[col] : bias1[col - N0];
#pragma unroll
        for (int rf = 0; rf < 2; rf++) {
            int rbase = rowblk + wr * 32 + rf * 16 + lg * 4;
#pragma unroll
            for (int i = 0; i < 4; i++) {
                float v = acc[rf][cf][i] + bv;
                if (SOFTPLUS) v = softplus_f(v);
                C[(size_t)(rbase + i) * N + col] = (OutT)v;
            }
        }
    }
}

// ---------------- k4: per-wave-private B strips -> barrier-free counted-vmcnt loop -----
__global__ __launch_bounds__(256) void k4_mfma(const _Float16* __restrict__ aqrq16,
                                               const _Float16* __restrict__ kern2,
                                               const float* __restrict__ kern_n,
                                               const float* __restrict__ norm_k,
                                               __hip_bfloat16* __restrict__ resp) {
    __shared__ _Float16 Bb[2][2][64 * 64];  // 32KB
    __shared__ _Float16 rql[64][72];        // 9.2KB
    __shared__ float scl[64];
    __shared__ float nkl[64];
    int tid = threadIdx.x, lane = tid & 63, wid = tid >> 6;
    int l15 = lane & 15, lg = lane >> 4;
    int b = blockIdx.x >> 7;
    int rc = (blockIdx.x >> 1) & 63;
    int mh = blockIdx.x & 1;
    int rowbase = rc * 64;
    float* knl = (float*)&Bb[1][0][0];      // 16KB alias, dead after scale phase

    auto stageB = [&](int a_, int buf, int sl) {
#pragma unroll
        for (int j = 0; j < 2; j++) {
            int c = wid * 2 + j;
            int m = c * 8 + (lane >> 3);
            int sa = ((lane & 7) ^ (lane >> 3)) * 8;
            lds_load16(&Bb[buf][sl][c * 512],
                       kern2 + (((size_t)(b * 64 + a_)) * Mc + mh * 64 + m) * DAc + sa);
        }
    };
    stageB(0, 0, 0);
    stageB(1, 0, 1);
    {   // kern_n[b] -> knl (16KB, async)
#pragma unroll
        for (int j = 0; j < 4; j++) {
            int c = wid * 4 + j;
            lds_load16(knl + c * 256, kern_n + (size_t)b * 4096 + c * 256 + lane * 4);
        }
    }

    // aq fragments (loop-invariant): 4 row-frags x 2 k-halves
    half8 aqp[4][2];
#pragma unroll
    for (int rf = 0; rf < 4; rf++)
#pragma unroll
        for (int kh = 0; kh < 2; kh++) {
            int rg = rowbase + rf * 16 + l15;
            int t_ = rg >> 3, h = rg & 7;
            aqp[rf][kh] = *(const half8*)(aqrq16 + ((size_t)(b * Tc + t_)) * 1024
                                          + h * 64 + kh * 32 + lg * 8);
        }
    {   // rq rows -> LDS f16 (16 halves per thread)
        int row = tid >> 2, q = tid & 3;
        int rg = rowbase + row;
        int t_ = rg >> 3, h = rg & 7;
        const _Float16* src = aqrq16 + ((size_t)(b * Tc + t_)) * 1024 + 512 + h * 64 + q * 16;
        *(half8*)&rql[row][q * 16] = *(const half8*)(src);
        *(half8*)&rql[row][q * 16 + 8] = *(const half8*)(src + 8);
    }
    if (tid < 64) nkl[tid] = norm_k[tid];
    __syncthreads();

    // ---- scale phase: wave handles 16 rows x 4 d-chunks; knl reads broadcast ----
    {
        int row = wid * 16 + (lane >> 2);
        int c = lane & 3;
        int rg = rowbase + row;
        int t_ = rg >> 3, h = rg & 7;
        const _Float16* aqg = aqrq16 + ((size_t)(b * Tc + t_)) * 1024 + h * 64;
        float accj[16];
#pragma unroll
        for (int j = 0; j < 16; j++) accj[j] = 0.f;
        float d1 = 0.f;
#pragma unroll
        for (int a2c = 0; a2c < 4; a2c++) {
            half8 aa0 = *(const half8*)(aqg + a2c * 16);
            half8 aa1 = *(const half8*)(aqg + a2c * 16 + 8);
            float aqv[16];
#pragma unroll
            for (int j = 0; j < 8; j++) { aqv[j] = (float)aa0[j]; aqv[8 + j] = (float)aa1[j]; }
#pragma unroll
            for (int a2l = 0; a2l < 16; a2l++) {
                int a2 = a2c * 16 + a2l;
                float av = aqv[a2l];
                d1 = fmaf(av, nkl[a2], d1);
                const float4* kr = (const float4*)(knl + a2 * 64 + c * 16);
#pragma unroll
                for (int j4 = 0; j4 < 4; j4++) {
                    float4 kv = kr[j4];
                    accj[j4 * 4 + 0] = fmaf(av, kv.x, accj[j4 * 4 + 0]);
                    accj[j4 * 4 + 1] = fmaf(av, kv.y, accj[j4 * 4 + 1]);
                    accj[j4 * 4 + 2] = fmaf(av, kv.z, accj[j4 * 4 + 2]);
                    accj[j4 * 4 + 3] = fmaf(av, kv.w, accj[j4 * 4 + 3]);
                }
            }
        }
        float sn = 0.f;
#pragma unroll
        for (int j = 0; j < 16; j++)
            sn = fmaf((float)rql[row][c * 16 + j], accj[j], sn);
        sn += __shfl_xor(sn, 1);
        sn += __shfl_xor(sn, 2);
        if (c == 0) {
            float den1 = d1 + EPSF;
            float den = sn / den1 + EPSF;
            scl[row] = 1.f / (den1 * den);
        }
    }
    __syncthreads();   // scl ready; knl dead; all prologue staging drained (vmcnt 0)

    f32x4 acc[4];
#pragma unroll
    for (int i = 0; i < 4; i++) acc[i] = (f32x4){0.f, 0.f, 0.f, 0.f};

    int mloc = wid * 16 + l15;                  // wave owns m-chunk [wid*16, wid*16+16)
    int cur = 0;
    for (int it = 0; it < 32; it++) {
        if (it < 31) {
            stageB(it * 2 + 2, cur ^ 1, 0);     // +2 per thread
            stageB(it * 2 + 3, cur ^ 1, 1);     // +2 -> 8 outstanding in steady state
            asm volatile("s_waitcnt vmcnt(4)" ::: "memory");  // current pair's 4 retired
        } else {
            asm volatile("s_waitcnt vmcnt(0)" ::: "memory");
        }
        __builtin_amdgcn_sched_barrier(0);
#pragma unroll
        for (int as = 0; as < 2; as++) {
            int a = it * 2 + as;
            half8 rb[4];
#pragma unroll
            for (int rf = 0; rf < 4; rf++) {
                _Float16 hv = rql[rf * 16 + l15][a];
                rb[rf] = (half8){hv, hv, hv, hv, hv, hv, hv, hv};
            }
#pragma unroll
            for (int kh = 0; kh < 2; kh++) {
                int ch = (kh * 4 + lg) ^ (mloc & 7);
                half8 bf = *(const half8*)&Bb[cur][as][mloc * 64 + ch * 8];
#pragma unroll
                for (int rf = 0; rf < 4; rf++)
                    acc[rf] = __builtin_amdgcn_mfma_f32_16x16x32_f16(
                        aqp[rf][kh] * rb[rf], bf, acc[rf], 0, 0, 0);
            }
        }
        cur ^= 1;
    }
#pragma unroll
    for (int rf = 0; rf < 4; rf++) {
#pragma unroll
        for (int i = 0; i < 4; i++) {
            int rl = rf * 16 + lg * 4 + i;
            int rg = rowbase + rl;
            float s = scl[rl];
            int t_ = rg >> 3, h = rg & 7;
            __hip_bfloat16* dst = resp + ((size_t)(b * Tc + t_)) * 1024 + h * DMc + mh * 64;
            dst[mloc] = __float2bfloat16(acc[rf][i] * s);
        }
    }
}

extern "C" void kernel_launch(void* const* d_in, const int* in_sizes, int n_in,
                              void* d_out, int out_size, void* d_ws, size_t ws_size,
                              hipStream_t stream) {
    const float* query      = (const float*)d_in[0];
    const float* matrix     = (const float*)d_in[1];
    const float* normalizer = (const float*)d_in[2];
    const float* addresses  = (const float*)d_in[3];
    const float* W_access   = (const float*)d_in[4];
    const float* b_access   = (const float*)d_in[5];
    const float* W_read     = (const float*)d_in[6];
    const float* b_read     = (const float*)d_in[7];
    const float* W_merge    = (const float*)d_in[8];
    const float* b_merge    = (const float*)d_in[9];
    float* out = (float*)d_out;
    (void)in_sizes; (void)n_in; (void)out_size; (void)ws_size;

    float* ws     = (float*)d_ws;
    float* norm_k = ws;                        // 64 (+pad to 128)
    float* kern_n = ws + 128;                  // 16384
    _Float16* aqrq16 = (_Float16*)(ws + 16512);               // 2,097,152 f16
    _Float16* kern2  = (_Float16*)(ws + 1065088);             // 2,097,152 f16
    __hip_bfloat16* qb   = (__hip_bfloat16*)(ws + 2113664);   // 2,097,152 bf16
    __hip_bfloat16* resp = (__hip_bfloat16*)(ws + 3162240);   // 2,097,152 bf16
    __hip_bfloat16* WpT  = (__hip_bfloat16*)(ws + 4210816);   // 1,048,576 bf16
    __hip_bfloat16* WmT  = (__hip_bfloat16*)(ws + 4735104);   // 1,048,576 bf16
    // total 5,259,392 floats = 21.0 MB

    hipLaunchKernelGGL(front_kern, dim3(2849), dim3(256), 0, stream,
                       addresses, matrix, normalizer, query,
                       W_access, W_read, W_merge,
                       kern2, kern_n, norm_k, qb, WpT, WmT);
    hipLaunchKernelGGL((gemm_bf16<true, _Float16>), dim3(32, 16), dim3(256), 0, stream,
                       qb, WpT, b_access, b_read, 512, aqrq16, 1024, 1024);
    hipLaunchKernelGGL(k4_mfma, dim3(512), dim3(256), 0, stream,
                       aqrq16, kern2, kern_n, norm_k, resp);
    hipLaunchKernelGGL((gemm_bf16<false, float>), dim3(32, 16), dim3(256), 0, stream,
                       resp, WmT, b_merge, b_merge, 2048, out, 1024, 1024);
}